// Round 11
// baseline (120.784 us; speedup 1.0000x reference)
//
#include <hip/hip_runtime.h>

#define SEQ    2048
#define NH     16
#define DMODEL 1024

typedef __attribute__((ext_vector_type(4)))  float f32x4;
typedef __attribute__((ext_vector_type(8)))  short s16x8;
typedef __attribute__((ext_vector_type(4)))  short s16x4;
typedef __attribute__((ext_vector_type(2)))  unsigned u32x2;

__device__ __forceinline__ float bf2f(unsigned short u){
  union { unsigned int i; float f; } v; v.i = ((unsigned int)u) << 16; return v.f;
}
__device__ __forceinline__ unsigned short f2bf(float f){        // RNE
  union { float f; unsigned int i; } v; v.f = f;
  unsigned int r = v.i + 0x7fffu + ((v.i >> 16) & 1u);
  return (unsigned short)(r >> 16);
}
__device__ __forceinline__ unsigned short f2bf_hu(float f){     // round-half-up
  union { float f; unsigned int i; } v; v.f = f;
  return (unsigned short)((v.i + 0x8000u) >> 16);
}
__device__ __forceinline__ float fast_exp2(float x){
  return __builtin_amdgcn_exp2f(x);          // v_exp_f32: 2^x
}
__device__ __forceinline__ void gld_lds16(const void* g, void* l){
  __builtin_amdgcn_global_load_lds((const __attribute__((address_space(1))) void*)g,
                                   (__attribute__((address_space(3))) void*)l,
                                   16, 0, 0);
}

// ---------------- prep: cast x to bf16 ----------------
__global__ __launch_bounds__(256) void k_cast_x(const float* __restrict__ x,
                                                unsigned short* __restrict__ hi){
  int i = blockIdx.x * 256 + threadIdx.x;
  f32x4 v = ((const f32x4*)x)[i];
  s16x4 h;
  #pragma unroll
  for (int j = 0; j < 4; ++j) h[j] = (short)f2bf(v[j]);
  ((s16x4*)hi)[i] = h;
}

// ------- prep: transpose W[k][n] -> Wt[n][k] bf16 -------
__global__ __launch_bounds__(256) void k_t_w(const float* __restrict__ W0,
                                             const float* __restrict__ W1,
                                             const float* __restrict__ W2,
                                             const float* __restrict__ W3,
                                             unsigned short* __restrict__ Wt){
  __shared__ float t[64][65];
  const float* Ws[4] = {W0, W1, W2, W3};
  const float* W = Ws[blockIdx.z];
  const int n0 = blockIdx.x * 64, k0 = blockIdx.y * 64;
  const int tid = threadIdx.x;
  #pragma unroll
  for (int i = 0; i < 16; ++i){
    int e = i * 256 + tid;
    int r = e >> 6, c = e & 63;
    t[r][c] = W[(size_t)(k0 + r) * 1024 + n0 + c];
  }
  __syncthreads();
  size_t base = ((size_t)blockIdx.z << 20);
  #pragma unroll
  for (int i = 0; i < 16; ++i){
    int e = i * 256 + tid;
    int nn = e >> 6, kk = e & 63;
    Wt[base + (size_t)(n0 + nn) * 1024 + k0 + kk] = f2bf(t[kk][nn]);
  }
}

// ---------- fused QKV GEMM: 64x128 tiles, grid (24,64) = 6 blocks/CU ----------
// B = Wt linear in n (n0>>10 uniform per block since N-tile=128 divides 1024).
// Q,K -> bf16 [4096][1024]; V -> bf16 V^T [2][16][64][2048].
__global__ __launch_bounds__(256, 6)
void gemm_qkv(const unsigned short* __restrict__ A,
              const unsigned short* __restrict__ B,
              const float* __restrict__ bq, const float* __restrict__ bk,
              const float* __restrict__ bv,
              unsigned short* __restrict__ Qb, unsigned short* __restrict__ Kb,
              unsigned short* __restrict__ Vt)
{
  __shared__ __align__(16) unsigned short lA[2][64 * 32];
  __shared__ __align__(16) unsigned short lB[2][128 * 32];
  const int tid = threadIdx.x;
  const int lane = tid & 63, w = tid >> 6;
  const int wm = w >> 1, wn = w & 1;
  const int lr = lane & 15, lq = lane >> 4;
  const int m0 = blockIdx.y * 64, n0 = blockIdx.x * 128;

  auto stage = [&](int buf, int k0){
    {
      int c = tid;                       // 256 chunks of 64x32 A-tile
      int row = c >> 2, cc = c & 3;
      gld_lds16(A + (size_t)(m0 + row) * 1024 + k0 + cc * 8, &lA[buf][c * 8]);
    }
    #pragma unroll
    for (int it = 0; it < 2; ++it){
      int c = it * 256 + tid;            // 512 chunks of 128x32 B-tile
      int row = c >> 2, cc = c & 3;
      gld_lds16(B + (size_t)(n0 + row) * 1024 + k0 + cc * 8, &lB[buf][c * 8]);
    }
  };

  f32x4 acc[2][4];
  #pragma unroll
  for (int i = 0; i < 2; ++i)
    #pragma unroll
    for (int j = 0; j < 4; ++j) acc[i][j] = (f32x4)0.0f;

  stage(0, 0);
  __syncthreads();
  for (int k0 = 0; k0 < 1024; k0 += 32){
    const int cur = (k0 >> 5) & 1;
    if (k0 + 32 < 1024) stage(cur ^ 1, k0 + 32);
    s16x8 fa[2], fb[4];
    #pragma unroll
    for (int f = 0; f < 2; ++f)
      fa[f] = *(const s16x8*)&lA[cur][(wm * 32 + f * 16 + lr) * 32 + lq * 8];
    #pragma unroll
    for (int f = 0; f < 4; ++f)
      fb[f] = *(const s16x8*)&lB[cur][(wn * 64 + f * 16 + lr) * 32 + lq * 8];
    #pragma unroll
    for (int i = 0; i < 2; ++i)
      #pragma unroll
      for (int j = 0; j < 4; ++j)
        acc[i][j] = __builtin_amdgcn_mfma_f32_16x16x32_bf16(fa[i], fb[j], acc[i][j], 0, 0, 0);
    __syncthreads();
  }

  const int mat = n0 >> 10;                 // 0=Q, 1=K, 2=V (uniform per block)
  const float* bias = (mat == 0) ? bq : (mat == 1) ? bk : bv;
  unsigned short* QK = (mat == 0) ? Qb : Kb;
  const int mb = m0 + wm * 32, nb = n0 + wn * 64;
  #pragma unroll
  for (int i = 0; i < 2; ++i){
    int row = mb + i * 16 + lq * 4;
    #pragma unroll
    for (int j = 0; j < 4; ++j){
      int col = (nb + j * 16 + lr) & 1023;
      float bs = bias[col];
      if (mat < 2){
        #pragma unroll
        for (int r = 0; r < 4; ++r)
          QK[(size_t)(row + r) * 1024 + col] = f2bf(acc[i][j][r] + bs);
      } else {
        int bb = row >> 11, s = row & 2047;
        int h = col >> 6, d = col & 63;
        s16x4 pk;
        #pragma unroll
        for (int r = 0; r < 4; ++r) pk[r] = (short)f2bf(acc[i][j][r] + bs);
        *(s16x4*)&Vt[(((size_t)(bb * NH + h) * 64 + d) << 11) + s] = pk;
      }
    }
  }
}

// ---------- O GEMM: 64x64 tiles bf16, fp32 out + bias ----------
// grid (16, 64) = 1024 blocks = 4/CU. Wave tile 32x32.
__global__ __launch_bounds__(256, 4)
void gemm_o(const unsigned short* __restrict__ A,
            const unsigned short* __restrict__ B,
            const float* __restrict__ bias,
            float* __restrict__ C)
{
  __shared__ __align__(16) unsigned short lA[2][64 * 32];
  __shared__ __align__(16) unsigned short lB[2][64 * 32];
  const int tid = threadIdx.x;
  const int lane = tid & 63, w = tid >> 6;
  const int wm = w >> 1, wn = w & 1;
  const int lr = lane & 15, lq = lane >> 4;
  const int m0 = blockIdx.y * 64, n0 = blockIdx.x * 64;

  auto stage = [&](int buf, int k0){
    int c = tid;                       // 256 chunks of each 64x32 tile
    int row = c >> 2, cc = c & 3;
    gld_lds16(A + (size_t)(m0 + row) * 1024 + k0 + cc * 8, &lA[buf][c * 8]);
    gld_lds16(B + (size_t)(n0 + row) * 1024 + k0 + cc * 8, &lB[buf][c * 8]);
  };

  f32x4 acc[2][2];
  #pragma unroll
  for (int i = 0; i < 2; ++i)
    #pragma unroll
    for (int j = 0; j < 2; ++j) acc[i][j] = (f32x4)0.0f;

  stage(0, 0);
  __syncthreads();
  for (int k0 = 0; k0 < 1024; k0 += 32){
    const int cur = (k0 >> 5) & 1;
    if (k0 + 32 < 1024) stage(cur ^ 1, k0 + 32);
    s16x8 fa[2], fb[2];
    #pragma unroll
    for (int f = 0; f < 2; ++f){
      fa[f] = *(const s16x8*)&lA[cur][(wm * 32 + f * 16 + lr) * 32 + lq * 8];
      fb[f] = *(const s16x8*)&lB[cur][(wn * 32 + f * 16 + lr) * 32 + lq * 8];
    }
    #pragma unroll
    for (int i = 0; i < 2; ++i)
      #pragma unroll
      for (int j = 0; j < 2; ++j)
        acc[i][j] = __builtin_amdgcn_mfma_f32_16x16x32_bf16(fa[i], fb[j], acc[i][j], 0, 0, 0);
    __syncthreads();
  }

  const int mb = m0 + wm * 32, nb = n0 + wn * 32;
  #pragma unroll
  for (int i = 0; i < 2; ++i){
    int row = mb + i * 16 + lq * 4;
    #pragma unroll
    for (int j = 0; j < 2; ++j){
      int col = nb + j * 16 + lr;
      float bs = bias[col];
      #pragma unroll
      for (int r = 0; r < 4; ++r)
        C[(size_t)(row + r) * 1024 + col] = acc[i][j][r] + bs;
    }
  }
}

// ---- causal flash attention: r5 topology (4 waves, 16-wave/CU cap) + S^T ----
// grid (32 bh, 32 qt-slots); qt = 31 - blockIdx.y (LPT). 256 threads = 4 waves;
// wave w owns q-rows qt*64 + w*16 .. +15. K/V^T 64x64 tiles double-buffered,
// XOR-swizzled via pre-swizzled global source. S^T = mfma(K,Q): C lane =
// (q-col = lr, tokens lq*4+r consecutive) -> cheap diagonal mask and P packs
// to ONE ds_write_b64 per 16-token sub-tile. Fixed-shift softmax p = 2^(s-11),
// lane-local ls, epilogue reduce.
__global__ __launch_bounds__(256, 4)
void attn_fwd(const unsigned short* __restrict__ Qg,
              const unsigned short* __restrict__ Kg,
              const unsigned short* __restrict__ Vtg,
              unsigned short* __restrict__ Oh)
{
  __shared__ __align__(16) unsigned short lK[2][64 * 64];
  __shared__ __align__(16) unsigned short lV[2][64 * 64];
  __shared__ __align__(16) unsigned short lP[4][16 * 64];
  const int tid = threadIdx.x;
  const int lane = tid & 63, w = tid >> 6;    // 4 waves
  const int lr = lane & 15, lq = lane >> 4;
  const int bh = blockIdx.x;
  const int b = bh >> 4, h = bh & 15;
  const int qt = 31 - blockIdx.y;
  const int qrow = qt * 64 + w * 16;

  const float qscale = 0.125f * 1.44269504088896f;   // 1/sqrt(dk) * log2e
  const float FIXMAX = 11.0f;

  // Q fragments (B-operand: lane holds col q = lr, k = lq*8..+7 per 32-k chunk)
  const unsigned short* qp = Qg + (size_t)(b * SEQ + qrow + lr) * 1024 + h * 64 + lq * 8;
  s16x8 q0 = *(const s16x8*)qp;
  s16x8 q1 = *(const s16x8*)(qp + 32);
  #pragma unroll
  for (int j = 0; j < 8; ++j){
    q0[j] = (short)f2bf(bf2f((unsigned short)q0[j]) * qscale);
    q1[j] = (short)f2bf(bf2f((unsigned short)q1[j]) * qscale);
  }

  float ls = 0.f;
  f32x4 accO[4];
  #pragma unroll
  for (int dt = 0; dt < 4; ++dt) accO[dt] = (f32x4)0.0f;

  auto stage = [&](int buf, int kt){
    const int kc0 = kt * 64;
    #pragma unroll
    for (int it = 0; it < 2; ++it){
      int c = it * 256 + tid;          // 0..511 chunks
      int row = c >> 3, sc = c & 7;
      int lc = sc ^ (row & 7);         // inverse-swizzled source chunk
      gld_lds16(Kg + (size_t)(b * SEQ + kc0 + row) * 1024 + h * 64 + lc * 8, &lK[buf][c * 8]);
      gld_lds16(Vtg + ((size_t)(bh * 64 + row) << 11) + kc0 + lc * 8, &lV[buf][c * 8]);
    }
  };

  stage(0, 0);
  __syncthreads();
  for (int kt = 0; kt <= qt; ++kt){
    const int cur = kt & 1;
    if (kt < qt) stage(cur ^ 1, kt + 1);
    const bool diag = (kt == qt);

    // S^T = K.Q : A = K (row = token = st*16+lr), B = Q (col = q-row)
    f32x4 s4[4];
    #pragma unroll
    for (int st = 0; st < 4; ++st){
      if (diag && st > w){ s4[st] = (f32x4)(-1e30f); continue; }  // fully masked
      int tok = st * 16 + lr;
      const char* kb = (const char*)&lK[cur][0] + tok * 128;
      s16x8 kf0 = *(const s16x8*)(kb + (((0 + lq) ^ (tok & 7)) << 4));
      s16x8 kf1 = *(const s16x8*)(kb + (((4 + lq) ^ (tok & 7)) << 4));
      f32x4 z = (f32x4)0.0f;
      z = __builtin_amdgcn_mfma_f32_16x16x32_bf16(kf0, q0, z, 0, 0, 0);
      z = __builtin_amdgcn_mfma_f32_16x16x32_bf16(kf1, q1, z, 0, 0, 0);
      if (diag && st == w){            // partial diag: token lq*4+r vs q lr
        #pragma unroll
        for (int r = 0; r < 4; ++r)
          if (lq * 4 + r > lr) z[r] = -1e30f;
      }
      s4[st] = z;
    }

    // fixed-shift softmax + packed P write (1x ds_write_b64 = 4 tokens)
    char* pb = (char*)&lP[w][0];
    #pragma unroll
    for (int st = 0; st < 4; ++st){
      float p0 = fast_exp2(s4[st][0] - FIXMAX);
      float p1 = fast_exp2(s4[st][1] - FIXMAX);
      float p2 = fast_exp2(s4[st][2] - FIXMAX);
      float p3 = fast_exp2(s4[st][3] - FIXMAX);
      ls += (p0 + p1) + (p2 + p3);
      u32x2 d;
      d[0] = ((unsigned)f2bf_hu(p1) << 16) | f2bf_hu(p0);
      d[1] = ((unsigned)f2bf_hu(p3) << 16) | f2bf_hu(p2);
      int base = lr * 128 + ((st * 32 + lq * 8) ^ ((lr & 7) << 4));
      *(u32x2*)(pb + base) = d;
    }
    asm volatile("s_waitcnt lgkmcnt(0)" ::: "memory");
    // P fragments (A-operand: row = q = lr, k = tokens)
    s16x8 pf0 = *(const s16x8*)(pb + lr * 128 + (((0 + lq) << 4) ^ ((lr & 7) << 4)));
    s16x8 pf1 = *(const s16x8*)(pb + lr * 128 + (((4 + lq) << 4) ^ ((lr & 7) << 4)));

    // O += P.V : A = P (row = q), B = V^T (col = d = dt*16+lr), k = tokens
    #pragma unroll
    for (int dt = 0; dt < 4; ++dt){
      int drow = dt * 16 + lr;
      const char* vb = (const char*)&lV[cur][0] + drow * 128;
      s16x8 vf0 = *(const s16x8*)(vb + (((0 + lq) ^ (drow & 7)) << 4));
      s16x8 vf1 = *(const s16x8*)(vb + (((4 + lq) ^ (drow & 7)) << 4));
      accO[dt] = __builtin_amdgcn_mfma_f32_16x16x32_bf16(pf0, vf0, accO[dt], 0, 0, 0);
      accO[dt] = __builtin_amdgcn_mfma_f32_16x16x32_bf16(pf1, vf1, accO[dt], 0, 0, 0);
    }
    __syncthreads();
  }

  // epilogue: reduce ls (lane holds partial for q = lr), normalize, store O
  float t = ls;
  t += __shfl_xor(t, 16);
  t += __shfl_xor(t, 32);            // lane now holds total for q = its lr
  #pragma unroll
  for (int r = 0; r < 4; ++r){
    float rn = 1.0f / __shfl(t, lq * 4 + r);
    #pragma unroll
    for (int dt = 0; dt < 4; ++dt){
      size_t off = (size_t)(b * SEQ + qrow + lq * 4 + r) * 1024 + h * 64 + dt * 16 + lr;
      Oh[off] = f2bf(accO[dt][r] * rn);
    }
  }
}

// ---------------- host launch ----------------
extern "C" void kernel_launch(void* const* d_in, const int* in_sizes, int n_in,
                              void* d_out, int out_size, void* d_ws, size_t ws_size,
                              hipStream_t stream){
  (void)in_sizes; (void)n_in; (void)out_size; (void)ws_size;
  const float* x  = (const float*)d_in[0];
  const float* Wq = (const float*)d_in[1];
  const float* bq = (const float*)d_in[2];
  const float* Wk = (const float*)d_in[3];
  const float* bk = (const float*)d_in[4];
  const float* Wv = (const float*)d_in[5];
  const float* bv = (const float*)d_in[6];
  const float* Wo = (const float*)d_in[7];
  const float* bo = (const float*)d_in[8];

  const size_t NT = 4096;            // tokens
  unsigned short* xh  = (unsigned short*)d_ws;
  unsigned short* wt  = xh + NT * 1024;         // [4][1024][1024] (linear in n)
  unsigned short* Qb  = wt + 4u * 1024 * 1024;
  unsigned short* Kb  = Qb + NT * 1024;
  unsigned short* Vt  = Kb + NT * 1024;         // [2][16][64][2048]
  unsigned short* Ohb = Vt + NT * 1024;

  k_cast_x<<<4096, 256, 0, stream>>>(x, xh);
  k_t_w<<<dim3(16, 16, 4), 256, 0, stream>>>(Wq, Wk, Wv, Wo, wt);

  gemm_qkv<<<dim3(24, 64), 256, 0, stream>>>(xh, wt, bq, bk, bv, Qb, Kb, Vt);

  attn_fwd<<<dim3(32, 32), 256, 0, stream>>>(Qb, Kb, Vt, Ohb);

  const size_t WM = (size_t)1024 * 1024;
  gemm_o<<<dim3(16, 64), 256, 0, stream>>>(Ohb, wt + 3 * WM, bo, (float*)d_out);
}

// Round 12
// 114.707 us; speedup vs baseline: 1.0530x; 1.0530x over previous
//
#include <hip/hip_runtime.h>

#define SEQ    2048
#define NH     16
#define DMODEL 1024

typedef __attribute__((ext_vector_type(4)))  float f32x4;
typedef __attribute__((ext_vector_type(8)))  short s16x8;
typedef __attribute__((ext_vector_type(4)))  short s16x4;
typedef __attribute__((ext_vector_type(2)))  unsigned u32x2;

__device__ __forceinline__ float bf2f(unsigned short u){
  union { unsigned int i; float f; } v; v.i = ((unsigned int)u) << 16; return v.f;
}
__device__ __forceinline__ unsigned short f2bf(float f){        // RNE
  union { float f; unsigned int i; } v; v.f = f;
  unsigned int r = v.i + 0x7fffu + ((v.i >> 16) & 1u);
  return (unsigned short)(r >> 16);
}
__device__ __forceinline__ unsigned short f2bf_hu(float f){     // round-half-up
  union { float f; unsigned int i; } v; v.f = f;
  return (unsigned short)((v.i + 0x8000u) >> 16);
}
__device__ __forceinline__ float fast_exp2(float x){
  return __builtin_amdgcn_exp2f(x);          // v_exp_f32: 2^x
}
__device__ __forceinline__ void gld_lds16(const void* g, void* l){
  __builtin_amdgcn_global_load_lds((const __attribute__((address_space(1))) void*)g,
                                   (__attribute__((address_space(3))) void*)l,
                                   16, 0, 0);
}

// ---------------- prep: cast x to bf16 ----------------
__global__ __launch_bounds__(256) void k_cast_x(const float* __restrict__ x,
                                                unsigned short* __restrict__ hi){
  int i = blockIdx.x * 256 + threadIdx.x;
  f32x4 v = ((const f32x4*)x)[i];
  s16x4 h;
  #pragma unroll
  for (int j = 0; j < 4; ++j) h[j] = (short)f2bf(v[j]);
  ((s16x4*)hi)[i] = h;
}

// ------- prep: transpose W[k][n] -> Wt[n][k] bf16 -------
__global__ __launch_bounds__(256) void k_t_w(const float* __restrict__ W0,
                                             const float* __restrict__ W1,
                                             const float* __restrict__ W2,
                                             const float* __restrict__ W3,
                                             unsigned short* __restrict__ Wt){
  __shared__ float t[64][65];
  const float* Ws[4] = {W0, W1, W2, W3};
  const float* W = Ws[blockIdx.z];
  const int n0 = blockIdx.x * 64, k0 = blockIdx.y * 64;
  const int tid = threadIdx.x;
  #pragma unroll
  for (int i = 0; i < 16; ++i){
    int e = i * 256 + tid;
    int r = e >> 6, c = e & 63;
    t[r][c] = W[(size_t)(k0 + r) * 1024 + n0 + c];
  }
  __syncthreads();
  size_t base = ((size_t)blockIdx.z << 20);
  #pragma unroll
  for (int i = 0; i < 16; ++i){
    int e = i * 256 + tid;
    int nn = e >> 6, kk = e & 63;
    Wt[base + (size_t)(n0 + nn) * 1024 + k0 + kk] = f2bf(t[kk][nn]);
  }
}

// ---- fused QKV GEMM: 128x96 tiles, grid (32,32) = 1024 blocks = 4/CU ----
// B = Wt linear in n. Each 16-col fragment lies inside one matrix (1024%16==0)
// -> per-fragment mat select. Q,K -> bf16 [4096][1024]; V -> V^T [2][16][64][2048].
__global__ __launch_bounds__(256, 4)
void gemm_qkv(const unsigned short* __restrict__ A,
              const unsigned short* __restrict__ B,
              const float* __restrict__ bq, const float* __restrict__ bk,
              const float* __restrict__ bv,
              unsigned short* __restrict__ Qb, unsigned short* __restrict__ Kb,
              unsigned short* __restrict__ Vt)
{
  __shared__ __align__(16) unsigned short lA[2][128 * 32];
  __shared__ __align__(16) unsigned short lB[2][96 * 32];
  const int tid = threadIdx.x;
  const int lane = tid & 63, w = tid >> 6;
  const int wm = w >> 1, wn = w & 1;
  const int lr = lane & 15, lq = lane >> 4;
  const int m0 = blockIdx.y * 128, n0 = blockIdx.x * 96;

  auto stage = [&](int buf, int k0){
    #pragma unroll
    for (int it = 0; it < 2; ++it){
      int c = it * 256 + tid;            // A: 512 chunks of 128x32
      int row = c >> 2, cc = c & 3;
      gld_lds16(A + (size_t)(m0 + row) * 1024 + k0 + cc * 8, &lA[buf][c * 8]);
    }
    #pragma unroll
    for (int it = 0; it < 2; ++it){
      int c = it * 256 + tid;            // B: 384 chunks of 96x32
      if (c < 384){
        int row = c >> 2, cc = c & 3;
        gld_lds16(B + (size_t)(n0 + row) * 1024 + k0 + cc * 8, &lB[buf][c * 8]);
      }
    }
  };

  f32x4 acc[4][3];
  #pragma unroll
  for (int i = 0; i < 4; ++i)
    #pragma unroll
    for (int j = 0; j < 3; ++j) acc[i][j] = (f32x4)0.0f;

  stage(0, 0);
  __syncthreads();
  for (int k0 = 0; k0 < 1024; k0 += 32){
    const int cur = (k0 >> 5) & 1;
    if (k0 + 32 < 1024) stage(cur ^ 1, k0 + 32);
    s16x8 fa[4], fb[3];
    #pragma unroll
    for (int f = 0; f < 4; ++f)
      fa[f] = *(const s16x8*)&lA[cur][(wm * 64 + f * 16 + lr) * 32 + lq * 8];
    #pragma unroll
    for (int f = 0; f < 3; ++f)
      fb[f] = *(const s16x8*)&lB[cur][(wn * 48 + f * 16 + lr) * 32 + lq * 8];
    #pragma unroll
    for (int i = 0; i < 4; ++i)
      #pragma unroll
      for (int j = 0; j < 3; ++j)
        acc[i][j] = __builtin_amdgcn_mfma_f32_16x16x32_bf16(fa[i], fb[j], acc[i][j], 0, 0, 0);
    __syncthreads();
  }

  const int mb = m0 + wm * 64, nb = n0 + wn * 48;
  #pragma unroll
  for (int i = 0; i < 4; ++i){
    int row = mb + i * 16 + lq * 4;
    #pragma unroll
    for (int j = 0; j < 3; ++j){
      int col = nb + j * 16 + lr;           // 0..3071
      int mat = col >> 10, cm = col & 1023; // frag-uniform mat (16 | 1024)
      float bs = ((mat == 0) ? bq : (mat == 1) ? bk : bv)[cm];
      if (mat < 2){
        unsigned short* QK = mat ? Kb : Qb;
        #pragma unroll
        for (int r = 0; r < 4; ++r)
          QK[(size_t)(row + r) * 1024 + cm] = f2bf(acc[i][j][r] + bs);
      } else {
        int bb = row >> 11, s = row & 2047;
        int h = cm >> 6, d = cm & 63;
        s16x4 pk;
        #pragma unroll
        for (int r = 0; r < 4; ++r) pk[r] = (short)f2bf(acc[i][j][r] + bs);
        *(s16x4*)&Vt[(((size_t)(bb * NH + h) * 64 + d) << 11) + s] = pk;
      }
    }
  }
}

// ---------- O GEMM: 64x64 tiles bf16, fp32 out + bias ----------
// grid (16, 64) = 1024 blocks = 4/CU. Wave tile 32x32.
__global__ __launch_bounds__(256, 4)
void gemm_o(const unsigned short* __restrict__ A,
            const unsigned short* __restrict__ B,
            const float* __restrict__ bias,
            float* __restrict__ C)
{
  __shared__ __align__(16) unsigned short lA[2][64 * 32];
  __shared__ __align__(16) unsigned short lB[2][64 * 32];
  const int tid = threadIdx.x;
  const int lane = tid & 63, w = tid >> 6;
  const int wm = w >> 1, wn = w & 1;
  const int lr = lane & 15, lq = lane >> 4;
  const int m0 = blockIdx.y * 64, n0 = blockIdx.x * 64;

  auto stage = [&](int buf, int k0){
    int c = tid;                       // 256 chunks of each 64x32 tile
    int row = c >> 2, cc = c & 3;
    gld_lds16(A + (size_t)(m0 + row) * 1024 + k0 + cc * 8, &lA[buf][c * 8]);
    gld_lds16(B + (size_t)(n0 + row) * 1024 + k0 + cc * 8, &lB[buf][c * 8]);
  };

  f32x4 acc[2][2];
  #pragma unroll
  for (int i = 0; i < 2; ++i)
    #pragma unroll
    for (int j = 0; j < 2; ++j) acc[i][j] = (f32x4)0.0f;

  stage(0, 0);
  __syncthreads();
  for (int k0 = 0; k0 < 1024; k0 += 32){
    const int cur = (k0 >> 5) & 1;
    if (k0 + 32 < 1024) stage(cur ^ 1, k0 + 32);
    s16x8 fa[2], fb[2];
    #pragma unroll
    for (int f = 0; f < 2; ++f){
      fa[f] = *(const s16x8*)&lA[cur][(wm * 32 + f * 16 + lr) * 32 + lq * 8];
      fb[f] = *(const s16x8*)&lB[cur][(wn * 32 + f * 16 + lr) * 32 + lq * 8];
    }
    #pragma unroll
    for (int i = 0; i < 2; ++i)
      #pragma unroll
      for (int j = 0; j < 2; ++j)
        acc[i][j] = __builtin_amdgcn_mfma_f32_16x16x32_bf16(fa[i], fb[j], acc[i][j], 0, 0, 0);
    __syncthreads();
  }

  const int mb = m0 + wm * 32, nb = n0 + wn * 32;
  #pragma unroll
  for (int i = 0; i < 2; ++i){
    int row = mb + i * 16 + lq * 4;
    #pragma unroll
    for (int j = 0; j < 2; ++j){
      int col = nb + j * 16 + lr;
      float bs = bias[col];
      #pragma unroll
      for (int r = 0; r < 4; ++r)
        C[(size_t)(row + r) * 1024 + col] = acc[i][j][r] + bs;
    }
  }
}

// ---- causal flash attention: r5 topology (4 waves, 16-wave/CU cap) + S^T ----
// grid (32 bh, 32 qt-slots); qt = 31 - blockIdx.y (LPT). 256 threads = 4 waves;
// wave w owns q-rows qt*64 + w*16 .. +15. K/V^T 64x64 tiles double-buffered,
// XOR-swizzled via pre-swizzled global source. S^T = mfma(K,Q): C lane =
// (q-col = lr, tokens lq*4+r consecutive) -> cheap diagonal mask and P packs
// to ONE ds_write_b64 per 16-token sub-tile. Fixed-shift softmax p = 2^(s-11),
// lane-local ls, epilogue reduce.
__global__ __launch_bounds__(256, 4)
void attn_fwd(const unsigned short* __restrict__ Qg,
              const unsigned short* __restrict__ Kg,
              const unsigned short* __restrict__ Vtg,
              unsigned short* __restrict__ Oh)
{
  __shared__ __align__(16) unsigned short lK[2][64 * 64];
  __shared__ __align__(16) unsigned short lV[2][64 * 64];
  __shared__ __align__(16) unsigned short lP[4][16 * 64];
  const int tid = threadIdx.x;
  const int lane = tid & 63, w = tid >> 6;    // 4 waves
  const int lr = lane & 15, lq = lane >> 4;
  const int bh = blockIdx.x;
  const int b = bh >> 4, h = bh & 15;
  const int qt = 31 - blockIdx.y;
  const int qrow = qt * 64 + w * 16;

  const float qscale = 0.125f * 1.44269504088896f;   // 1/sqrt(dk) * log2e
  const float FIXMAX = 11.0f;

  // Q fragments (B-operand: lane holds col q = lr, k = lq*8..+7 per 32-k chunk)
  const unsigned short* qp = Qg + (size_t)(b * SEQ + qrow + lr) * 1024 + h * 64 + lq * 8;
  s16x8 q0 = *(const s16x8*)qp;
  s16x8 q1 = *(const s16x8*)(qp + 32);
  #pragma unroll
  for (int j = 0; j < 8; ++j){
    q0[j] = (short)f2bf(bf2f((unsigned short)q0[j]) * qscale);
    q1[j] = (short)f2bf(bf2f((unsigned short)q1[j]) * qscale);
  }

  float ls = 0.f;
  f32x4 accO[4];
  #pragma unroll
  for (int dt = 0; dt < 4; ++dt) accO[dt] = (f32x4)0.0f;

  auto stage = [&](int buf, int kt){
    const int kc0 = kt * 64;
    #pragma unroll
    for (int it = 0; it < 2; ++it){
      int c = it * 256 + tid;          // 0..511 chunks
      int row = c >> 3, sc = c & 7;
      int lc = sc ^ (row & 7);         // inverse-swizzled source chunk
      gld_lds16(Kg + (size_t)(b * SEQ + kc0 + row) * 1024 + h * 64 + lc * 8, &lK[buf][c * 8]);
      gld_lds16(Vtg + ((size_t)(bh * 64 + row) << 11) + kc0 + lc * 8, &lV[buf][c * 8]);
    }
  };

  stage(0, 0);
  __syncthreads();
  for (int kt = 0; kt <= qt; ++kt){
    const int cur = kt & 1;
    if (kt < qt) stage(cur ^ 1, kt + 1);
    const bool diag = (kt == qt);

    // S^T = K.Q : A = K (row = token = st*16+lr), B = Q (col = q-row)
    f32x4 s4[4];
    #pragma unroll
    for (int st = 0; st < 4; ++st){
      if (diag && st > w){ s4[st] = (f32x4)(-1e30f); continue; }  // fully masked
      int tok = st * 16 + lr;
      const char* kb = (const char*)&lK[cur][0] + tok * 128;
      s16x8 kf0 = *(const s16x8*)(kb + (((0 + lq) ^ (tok & 7)) << 4));
      s16x8 kf1 = *(const s16x8*)(kb + (((4 + lq) ^ (tok & 7)) << 4));
      f32x4 z = (f32x4)0.0f;
      z = __builtin_amdgcn_mfma_f32_16x16x32_bf16(kf0, q0, z, 0, 0, 0);
      z = __builtin_amdgcn_mfma_f32_16x16x32_bf16(kf1, q1, z, 0, 0, 0);
      if (diag && st == w){            // partial diag: token lq*4+r vs q lr
        #pragma unroll
        for (int r = 0; r < 4; ++r)
          if (lq * 4 + r > lr) z[r] = -1e30f;
      }
      s4[st] = z;
    }

    // fixed-shift softmax + packed P write (1x ds_write_b64 = 4 tokens)
    char* pb = (char*)&lP[w][0];
    #pragma unroll
    for (int st = 0; st < 4; ++st){
      float p0 = fast_exp2(s4[st][0] - FIXMAX);
      float p1 = fast_exp2(s4[st][1] - FIXMAX);
      float p2 = fast_exp2(s4[st][2] - FIXMAX);
      float p3 = fast_exp2(s4[st][3] - FIXMAX);
      ls += (p0 + p1) + (p2 + p3);
      u32x2 d;
      d[0] = ((unsigned)f2bf_hu(p1) << 16) | f2bf_hu(p0);
      d[1] = ((unsigned)f2bf_hu(p3) << 16) | f2bf_hu(p2);
      int base = lr * 128 + ((st * 32 + lq * 8) ^ ((lr & 7) << 4));
      *(u32x2*)(pb + base) = d;
    }
    asm volatile("s_waitcnt lgkmcnt(0)" ::: "memory");
    // P fragments (A-operand: row = q = lr, k = tokens)
    s16x8 pf0 = *(const s16x8*)(pb + lr * 128 + (((0 + lq) << 4) ^ ((lr & 7) << 4)));
    s16x8 pf1 = *(const s16x8*)(pb + lr * 128 + (((4 + lq) << 4) ^ ((lr & 7) << 4)));

    // O += P.V : A = P (row = q), B = V^T (col = d = dt*16+lr), k = tokens
    #pragma unroll
    for (int dt = 0; dt < 4; ++dt){
      int drow = dt * 16 + lr;
      const char* vb = (const char*)&lV[cur][0] + drow * 128;
      s16x8 vf0 = *(const s16x8*)(vb + (((0 + lq) ^ (drow & 7)) << 4));
      s16x8 vf1 = *(const s16x8*)(vb + (((4 + lq) ^ (drow & 7)) << 4));
      accO[dt] = __builtin_amdgcn_mfma_f32_16x16x32_bf16(pf0, vf0, accO[dt], 0, 0, 0);
      accO[dt] = __builtin_amdgcn_mfma_f32_16x16x32_bf16(pf1, vf1, accO[dt], 0, 0, 0);
    }
    __syncthreads();
  }

  // epilogue: reduce ls (lane holds partial for q = lr), normalize, store O
  float t = ls;
  t += __shfl_xor(t, 16);
  t += __shfl_xor(t, 32);            // lane now holds total for q = its lr
  #pragma unroll
  for (int r = 0; r < 4; ++r){
    float rn = 1.0f / __shfl(t, lq * 4 + r);
    #pragma unroll
    for (int dt = 0; dt < 4; ++dt){
      size_t off = (size_t)(b * SEQ + qrow + lq * 4 + r) * 1024 + h * 64 + dt * 16 + lr;
      Oh[off] = f2bf(accO[dt][r] * rn);
    }
  }
}

// ---------------- host launch ----------------
extern "C" void kernel_launch(void* const* d_in, const int* in_sizes, int n_in,
                              void* d_out, int out_size, void* d_ws, size_t ws_size,
                              hipStream_t stream){
  (void)in_sizes; (void)n_in; (void)out_size; (void)ws_size;
  const float* x  = (const float*)d_in[0];
  const float* Wq = (const float*)d_in[1];
  const float* bq = (const float*)d_in[2];
  const float* Wk = (const float*)d_in[3];
  const float* bk = (const float*)d_in[4];
  const float* Wv = (const float*)d_in[5];
  const float* bv = (const float*)d_in[6];
  const float* Wo = (const float*)d_in[7];
  const float* bo = (const float*)d_in[8];

  const size_t NT = 4096;            // tokens
  unsigned short* xh  = (unsigned short*)d_ws;
  unsigned short* wt  = xh + NT * 1024;         // [4][1024][1024] (linear in n)
  unsigned short* Qb  = wt + 4u * 1024 * 1024;
  unsigned short* Kb  = Qb + NT * 1024;
  unsigned short* Vt  = Kb + NT * 1024;         // [2][16][64][2048]
  unsigned short* Ohb = Vt + NT * 1024;

  k_cast_x<<<4096, 256, 0, stream>>>(x, xh);
  k_t_w<<<dim3(16, 16, 4), 256, 0, stream>>>(Wq, Wk, Wv, Wo, wt);

  gemm_qkv<<<dim3(32, 32), 256, 0, stream>>>(xh, wt, bq, bk, bv, Qb, Kb, Vt);

  attn_fwd<<<dim3(32, 32), 256, 0, stream>>>(Qb, Kb, Vt, Ohb);

  const size_t WM = (size_t)1024 * 1024;
  gemm_o<<<dim3(16, 64), 256, 0, stream>>>(Ohb, wt + 3 * WM, bo, (float*)d_out);
}